// Round 2
// baseline (1245.550 us; speedup 1.0000x reference)
//
#include <hip/hip_runtime.h>
#include <stdint.h>
#include <math.h>

// ---------------------------------------------------------------- constants
#define DIM     1024
#define HID     4096
#define SEQ     2048
#define NB      4
#define NH      16
#define HD      64
#define NCHUNK  32          // SEQ / 64
#define MROWS   8192        // NB * SEQ

typedef unsigned short ushort_t;
typedef __attribute__((ext_vector_type(8))) short bf16x8;
typedef __attribute__((ext_vector_type(4))) float f32x4;

// ws layout (bytes) — peak use ~193.5 MB, proven non-faulting in round 1 (210 MB)
#define OFF_H    ((size_t)0)            // bf16 [8192][1024] (LN out; also CMS y buffer)
#define OFF_Q    ((size_t)16777216)     // bf16 [8192][1024]
#define OFF_K    ((size_t)33554432)     // bf16 [8192][1024]
#define OFF_V    ((size_t)50331648)     // bf16 [8192][1024]
#define OFF_P    ((size_t)67108864)     // f32 [64][32][4096]
#define OFF_KS   ((size_t)100663296)    // f32 [64][32][64]
#define OFF_X1   ((size_t)101187584)    // f32 [8192][1024]
#define OFF_WQT  ((size_t)134742016)    // bf16 [1024][1024]
#define OFF_WKT  ((size_t)136839168)
#define OFF_WVT  ((size_t)138936320)
#define OFF_WOT  ((size_t)141033472)
#define OFF_W1T  ((size_t)143130624)    // 3 x bf16 [4096][1024]
#define OFF_W2T  ((size_t)168296448)    // 3 x bf16 [1024][4096]
#define OFF_HIDB OFF_K                  // bf16 [8192][4096] overlaps K,V,P (dead at CMS time)

__device__ __forceinline__ float b2f(ushort_t u) {
    return __uint_as_float(((unsigned int)u) << 16);
}
__device__ __forceinline__ ushort_t f2b(float f) {
    unsigned int u = __float_as_uint(f);
    u += 0x7FFFu + ((u >> 16) & 1u);          // round-to-nearest-even
    return (ushort_t)(u >> 16);
}

// ---------------------------------------------------------------- transpose (f32 -> bf16)
// dst[c][r] = bf16(src[r][c]);  src is [R][C] f32.  grid (C/32, R/32), block (32,8)
__global__ void __launch_bounds__(256)
transpose_f32_bf16(const float* __restrict__ src, ushort_t* __restrict__ dst, int R, int C)
{
    __shared__ float t[32][33];
    const int bx = blockIdx.x * 32;   // col tile in src
    const int by = blockIdx.y * 32;   // row tile in src
    const int tx = threadIdx.x, ty = threadIdx.y;
    #pragma unroll
    for (int i = ty; i < 32; i += 8)
        t[i][tx] = src[(size_t)(by + i) * C + bx + tx];
    __syncthreads();
    #pragma unroll
    for (int i = ty; i < 32; i += 8)
        dst[(size_t)(bx + i) * R + by + tx] = f2b(t[tx][i]);
}

// ---------------------------------------------------------------- layernorm (f32 in, bf16 out)
// one block per row of 1024; 256 threads x 4 elems
__global__ void __launch_bounds__(256)
ln_fwd(const float* __restrict__ xin, const float* __restrict__ g,
       const float* __restrict__ be, ushort_t* __restrict__ out)
{
    const int row = blockIdx.x, tid = threadIdx.x;
    const float4 f = ((const float4*)(xin + (size_t)row * DIM))[tid];
    float v[4] = {f.x, f.y, f.z, f.w};
    float s  = v[0] + v[1] + v[2] + v[3];
    float ss = v[0]*v[0] + v[1]*v[1] + v[2]*v[2] + v[3]*v[3];
    #pragma unroll
    for (int off = 32; off; off >>= 1) {
        s  += __shfl_down(s, off);
        ss += __shfl_down(ss, off);
    }
    __shared__ float red[2][4];
    const int wave = tid >> 6, lane = tid & 63;
    if (lane == 0) { red[0][wave] = s; red[1][wave] = ss; }
    __syncthreads();
    s  = red[0][0] + red[0][1] + red[0][2] + red[0][3];
    ss = red[1][0] + red[1][1] + red[1][2] + red[1][3];
    const float mean = s * (1.0f / DIM);
    const float var  = ss * (1.0f / DIM) - mean * mean;
    const float rstd = rsqrtf(var + 1e-5f);
    ushort_t o[4];
    #pragma unroll
    for (int i = 0; i < 4; i++) {
        const int col = tid * 4 + i;
        o[i] = f2b((v[i] - mean) * rstd * g[col] + be[col]);
    }
    unsigned int lo = (unsigned int)o[0] | ((unsigned int)o[1] << 16);
    unsigned int hi = (unsigned int)o[2] | ((unsigned int)o[3] << 16);
    uint2 u2; u2.x = lo; u2.y = hi;
    *(uint2*)(out + (size_t)row * DIM + tid * 4) = u2;
}

// ---------------------------------------------------------------- GEMM (Bt)
// C[M,N] = epilogue(A[M,K] @ Bt[N,K]^T)   A,Bt bf16; bias/resid f32
#define ACT_NONE 0
#define ACT_ELU1 1
#define ACT_GELU 2

template<int ACT, bool BIAS, bool RES, bool OUTF32>
__global__ void __launch_bounds__(256)
gemm_bt(const ushort_t* __restrict__ A, const ushort_t* __restrict__ Bt,
        const float* __restrict__ bias, const float* __restrict__ resid,
        void* __restrict__ Cout, int M, int N, int K)
{
    __shared__ __align__(16) ushort_t As[128 * 32];
    __shared__ __align__(16) ushort_t Bs[128 * 32];
    const int tid  = threadIdx.x;
    const int wave = tid >> 6, lane = tid & 63;
    const int bm = blockIdx.x * 128, bn = blockIdx.y * 128;
    const int wm = (wave >> 1) * 64, wn = (wave & 1) * 64;
    const int srow = tid >> 2;            // 0..63 staging row
    const int skp  = (tid & 3) * 8;       // 0,8,16,24 (elem offset in k)
    const int mrow = lane & 15, kq = (lane >> 4) * 8;

    f32x4 acc[4][4] = {};

    const size_t arow0 = (size_t)(bm + srow)      * K;
    const size_t arow1 = (size_t)(bm + srow + 64) * K;
    const size_t brow0 = (size_t)(bn + srow)      * K;
    const size_t brow1 = (size_t)(bn + srow + 64) * K;

    for (int kt = 0; kt < K; kt += 32) {
        const uint4 a0 = *(const uint4*)(A  + arow0 + kt + skp);
        const uint4 a1 = *(const uint4*)(A  + arow1 + kt + skp);
        const uint4 b0 = *(const uint4*)(Bt + brow0 + kt + skp);
        const uint4 b1 = *(const uint4*)(Bt + brow1 + kt + skp);
        __syncthreads();
        *(uint4*)(As + srow * 32 + skp)        = a0;
        *(uint4*)(As + (srow + 64) * 32 + skp) = a1;
        *(uint4*)(Bs + srow * 32 + skp)        = b0;
        *(uint4*)(Bs + (srow + 64) * 32 + skp) = b1;
        __syncthreads();
        bf16x8 af[4], bfr[4];
        #pragma unroll
        for (int r = 0; r < 4; r++)
            af[r] = *(const bf16x8*)(As + (wm + r * 16 + mrow) * 32 + kq);
        #pragma unroll
        for (int c = 0; c < 4; c++)
            bfr[c] = *(const bf16x8*)(Bs + (wn + c * 16 + mrow) * 32 + kq);
        #pragma unroll
        for (int r = 0; r < 4; r++)
            #pragma unroll
            for (int c = 0; c < 4; c++)
                acc[r][c] = __builtin_amdgcn_mfma_f32_16x16x32_bf16(af[r], bfr[c], acc[r][c], 0, 0, 0);
    }

    // epilogue: C/D layout col=lane&15, row=(lane>>4)*4+reg   [m89/m91 verified]
    const int cr = (lane >> 4) * 4;
    const int cc = lane & 15;
    #pragma unroll
    for (int r = 0; r < 4; r++) {
        #pragma unroll
        for (int c = 0; c < 4; c++) {
            const int gc = bn + wn + c * 16 + cc;
            const float bv = BIAS ? bias[gc] : 0.0f;
            #pragma unroll
            for (int j = 0; j < 4; j++) {
                const int gr = bm + wm + r * 16 + cr + j;
                float vv = acc[r][c][j] + bv;
                if (ACT == ACT_ELU1) vv = (vv > 0.0f) ? (vv + 1.0f) : expf(vv);
                if (ACT == ACT_GELU) {
                    const float x3 = vv * vv * vv;
                    vv = 0.5f * vv * (1.0f + tanhf(0.7978845608028654f * (vv + 0.044715f * x3)));
                }
                const size_t oidx = (size_t)gr * N + gc;
                if (RES) vv += resid[oidx];
                if (OUTF32) ((float*)Cout)[oidx] = vv;
                else        ((ushort_t*)Cout)[oidx] = f2b(vv);
            }
        }
    }
}

// ---------------------------------------------------------------- attention
// phase 1: per chunk (b,h,c): M_c[d][e] = sum_t K[t,d]V[t,e]; ksum_c[d]
__global__ void __launch_bounds__(256)
attn_phase1(const ushort_t* __restrict__ K_, const ushort_t* __restrict__ V_,
            float* __restrict__ P, float* __restrict__ Ksum)
{
    const int c = blockIdx.x, h = blockIdx.y, b = blockIdx.z;
    __shared__ float Ks[64][64], Vs[64][64];
    const int tid = threadIdx.x;
    const size_t rowbase = (size_t)b * SEQ + c * 64;
    #pragma unroll
    for (int i = 0; i < 16; i++) {
        const int lin = tid + 256 * i;
        const int t = lin >> 6, d = lin & 63;
        const size_t gidx = (rowbase + t) * DIM + h * HD + d;
        Ks[t][d] = b2f(K_[gidx]);
        Vs[t][d] = b2f(V_[gidx]);
    }
    __syncthreads();
    const size_t pbase = (((size_t)b * NH + h) * NCHUNK + c) * 4096;
    #pragma unroll
    for (int i = 0; i < 16; i++) {
        const int lin = tid + 256 * i;
        const int d = lin >> 6, e = lin & 63;
        float a = 0.0f;
        for (int t = 0; t < 64; t++) a += Ks[t][d] * Vs[t][e];
        P[pbase + lin] = a;
    }
    if (tid < 64) {
        float a = 0.0f;
        for (int t = 0; t < 64; t++) a += Ks[t][tid];
        Ksum[(((size_t)b * NH + h) * NCHUNK + c) * 64 + tid] = a;
    }
}

// phase 1b: exclusive prefix over chunks, column-parallel.
// grid (16, 64): blockIdx.y = bh, blockIdx.x*256+tid = elem in [0,4096)
__global__ void __launch_bounds__(256)
attn_prefix(float* __restrict__ P, float* __restrict__ Ksum)
{
    const int bh = blockIdx.y;
    const int e  = blockIdx.x * 256 + threadIdx.x;
    const size_t base = (size_t)bh * NCHUNK * 4096 + e;
    float acc = 0.0f;
    #pragma unroll
    for (int c = 0; c < NCHUNK; c++) {
        const float t = P[base + (size_t)c * 4096];
        P[base + (size_t)c * 4096] = acc;
        acc += t;
    }
    if (blockIdx.x == 0 && threadIdx.x < 64) {
        const size_t kb = (size_t)bh * NCHUNK * 64 + threadIdx.x;
        float a = 0.0f;
        #pragma unroll
        for (int c = 0; c < NCHUNK; c++) {
            const float t = Ksum[kb + c * 64];
            Ksum[kb + c * 64] = a;
            a += t;
        }
    }
}

// phase 2: out = (Q@M_prev + causal(QK^T)@V) / (Q@ksum_prev + rowsum(S) + 1e-6)
// Out aliases Q_ (each block reads its tile to LDS before overwriting it)
__global__ void __launch_bounds__(256)
attn_phase2(const ushort_t* Q_, const ushort_t* __restrict__ K_,
            const ushort_t* __restrict__ V_, const float* __restrict__ P,
            const float* __restrict__ Ksum, ushort_t* Out)
{
    const int c = blockIdx.x, h = blockIdx.y, b = blockIdx.z;
    const int tid = threadIdx.x;
    __shared__ ushort_t Qs[64][66], KsB[64][66], VsB[64][66];
    __shared__ float S[64][65];
    __shared__ float Mp[64][64];
    __shared__ float kp[64];
    __shared__ float den[64];
    const size_t rowbase = (size_t)b * SEQ + c * 64;
    const size_t pbase = (((size_t)b * NH + h) * NCHUNK + c) * 4096;
    #pragma unroll
    for (int i = 0; i < 16; i++) {
        const int lin = tid + 256 * i;
        const int t = lin >> 6, d = lin & 63;
        const size_t gidx = (rowbase + t) * DIM + h * HD + d;
        Qs[t][d]  = Q_[gidx];
        KsB[t][d] = K_[gidx];
        VsB[t][d] = V_[gidx];
        Mp[t][d]  = P[pbase + lin];
    }
    if (tid < 64) kp[tid] = Ksum[(((size_t)b * NH + h) * NCHUNK + c) * 64 + tid];
    __syncthreads();
    // S = causal-masked Q K^T (inclusive diagonal)
    #pragma unroll
    for (int i = 0; i < 16; i++) {
        const int lin = tid + 256 * i;
        const int t = lin >> 6, ii = lin & 63;
        float a = 0.0f;
        if (ii <= t)
            for (int d = 0; d < 64; d++) a += b2f(Qs[t][d]) * b2f(KsB[ii][d]);
        S[t][ii] = a;
    }
    __syncthreads();
    if (tid < 64) {
        const int t = tid;
        float a = 1e-6f;
        for (int ii = 0; ii <= t; ii++) a += S[t][ii];
        for (int d = 0; d < 64; d++) a += b2f(Qs[t][d]) * kp[d];
        den[t] = a;
    }
    __syncthreads();
    #pragma unroll
    for (int i = 0; i < 16; i++) {
        const int lin = tid + 256 * i;
        const int t = lin >> 6, e = lin & 63;
        float a = 0.0f;
        for (int ii = 0; ii <= t; ii++) a += S[t][ii] * b2f(VsB[ii][e]);
        for (int d = 0; d < 64; d++)  a += b2f(Qs[t][d]) * Mp[d][e];
        Out[(rowbase + t) * DIM + h * HD + e] = f2b(a / den[t]);
    }
}

// ---------------------------------------------------------------- launcher
extern "C" void kernel_launch(void* const* d_in, const int* in_sizes, int n_in,
                              void* d_out, int out_size, void* d_ws, size_t ws_size,
                              hipStream_t stream)
{
    const float* x      = (const float*)d_in[0];
    const float* Wq     = (const float*)d_in[1];
    const float* Wk     = (const float*)d_in[2];
    const float* Wv     = (const float*)d_in[3];
    const float* Wo     = (const float*)d_in[4];
    const float* ln1g   = (const float*)d_in[5];
    const float* ln1b   = (const float*)d_in[6];
    const float* ln2g   = (const float*)d_in[7];
    const float* ln2b   = (const float*)d_in[8];
    const float* cw1    = (const float*)d_in[9];
    const float* cb1    = (const float*)d_in[10];
    const float* cw2    = (const float*)d_in[11];
    const float* cb2    = (const float*)d_in[12];

    char* ws = (char*)d_ws;
    ushort_t* h    = (ushort_t*)(ws + OFF_H);
    ushort_t* qb   = (ushort_t*)(ws + OFF_Q);
    ushort_t* kb   = (ushort_t*)(ws + OFF_K);
    ushort_t* vb   = (ushort_t*)(ws + OFF_V);
    float*    Pb   = (float*)(ws + OFF_P);
    float*    ksb  = (float*)(ws + OFF_KS);
    float*    x1   = (float*)(ws + OFF_X1);
    ushort_t* wqt  = (ushort_t*)(ws + OFF_WQT);
    ushort_t* wkt  = (ushort_t*)(ws + OFF_WKT);
    ushort_t* wvt  = (ushort_t*)(ws + OFF_WVT);
    ushort_t* wot  = (ushort_t*)(ws + OFF_WOT);
    ushort_t* w1t  = (ushort_t*)(ws + OFF_W1T);
    ushort_t* w2t  = (ushort_t*)(ws + OFF_W2T);
    ushort_t* hid  = (ushort_t*)(ws + OFF_HIDB);
    float*    outp = (float*)d_out;

    const dim3 tb(32, 8);
    // weight transposes -> bf16 [N][K] operand layout
    transpose_f32_bf16<<<dim3(32, 32), tb, 0, stream>>>(Wq, wqt, DIM, DIM);
    transpose_f32_bf16<<<dim3(32, 32), tb, 0, stream>>>(Wk, wkt, DIM, DIM);
    transpose_f32_bf16<<<dim3(32, 32), tb, 0, stream>>>(Wv, wvt, DIM, DIM);
    transpose_f32_bf16<<<dim3(32, 32), tb, 0, stream>>>(Wo, wot, DIM, DIM);
    for (int l = 0; l < 3; l++) {
        transpose_f32_bf16<<<dim3(128, 32), tb, 0, stream>>>(cw1 + (size_t)l * DIM * HID,
                                                             w1t + (size_t)l * HID * DIM, DIM, HID);
        transpose_f32_bf16<<<dim3(32, 128), tb, 0, stream>>>(cw2 + (size_t)l * HID * DIM,
                                                             w2t + (size_t)l * DIM * HID, HID, DIM);
    }

    // LN1: h = bf16(LN(x))
    ln_fwd<<<MROWS, 256, 0, stream>>>(x, ln1g, ln1b, h);

    // Q/K/V projections (ELU+1 on Q,K)
    gemm_bt<ACT_ELU1, false, false, false><<<dim3(64, 8), 256, 0, stream>>>(h, wqt, nullptr, nullptr, qb, MROWS, DIM, DIM);
    gemm_bt<ACT_ELU1, false, false, false><<<dim3(64, 8), 256, 0, stream>>>(h, wkt, nullptr, nullptr, kb, MROWS, DIM, DIM);
    gemm_bt<ACT_NONE, false, false, false><<<dim3(64, 8), 256, 0, stream>>>(h, wvt, nullptr, nullptr, vb, MROWS, DIM, DIM);

    // chunked linear attention
    attn_phase1<<<dim3(NCHUNK, NH, NB), 256, 0, stream>>>(kb, vb, Pb, ksb);
    attn_prefix<<<dim3(16, 64), 256, 0, stream>>>(Pb, ksb);
    attn_phase2<<<dim3(NCHUNK, NH, NB), 256, 0, stream>>>(qb, kb, vb, Pb, ksb, qb);

    // x1 = x + attn @ Wo   (f32)
    gemm_bt<ACT_NONE, false, true, true><<<dim3(64, 8), 256, 0, stream>>>(qb, wot, nullptr, x, x1, MROWS, DIM, DIM);

    // LN2: h = bf16(LN(x1))
    ln_fwd<<<MROWS, 256, 0, stream>>>(x1, ln2g, ln2b, h);

    // CMS: 3 chained MLPs; final one fuses +x1 and writes f32 d_out
    const ushort_t* cur = h;
    for (int l = 0; l < 3; l++) {
        gemm_bt<ACT_GELU, true, false, false><<<dim3(64, 32), 256, 0, stream>>>(
            cur, w1t + (size_t)l * HID * DIM, cb1 + (size_t)l * HID, nullptr, hid, MROWS, HID, DIM);
        if (l < 2) {
            gemm_bt<ACT_NONE, true, false, false><<<dim3(64, 8), 256, 0, stream>>>(
                hid, w2t + (size_t)l * DIM * HID, cb2 + (size_t)l * DIM, nullptr, h, MROWS, DIM, HID);
            cur = h;
        } else {
            gemm_bt<ACT_NONE, true, true, true><<<dim3(64, 8), 256, 0, stream>>>(
                hid, w2t + (size_t)l * DIM * HID, cb2 + (size_t)l * DIM, x1, outp, MROWS, DIM, HID);
        }
    }
    (void)in_sizes; (void)n_in; (void)out_size; (void)ws_size;
}

// Round 3
// 1047.706 us; speedup vs baseline: 1.1888x; 1.1888x over previous
//
#include <hip/hip_runtime.h>
#include <stdint.h>
#include <math.h>

// ---------------------------------------------------------------- constants
#define DIM     1024
#define HID     4096
#define SEQ     2048
#define NB      4
#define NH      16
#define HD      64
#define NCHUNK  32          // SEQ / 64
#define MROWS   8192        // NB * SEQ

typedef unsigned short ushort_t;
typedef __attribute__((ext_vector_type(8))) short bf16x8;
typedef __attribute__((ext_vector_type(4))) float f32x4;

// ws layout (bytes) — peak ~193.5 MB, proven non-faulting
#define OFF_H    ((size_t)0)            // bf16 [8192][1024]
#define OFF_Q    ((size_t)16777216)     // bf16 [8192][1024]
#define OFF_K    ((size_t)33554432)     // bf16 [8192][1024]
#define OFF_V    ((size_t)50331648)     // bf16 [8192][1024]
#define OFF_P    ((size_t)67108864)     // f32 [64][32][4096]
#define OFF_KS   ((size_t)100663296)    // f32 [64][32][64]
#define OFF_X1   ((size_t)101187584)    // f32 [8192][1024]
#define OFF_WQT  ((size_t)134742016)    // bf16 [1024][1024]
#define OFF_WKT  ((size_t)136839168)
#define OFF_WVT  ((size_t)138936320)
#define OFF_WOT  ((size_t)141033472)
#define OFF_W1T  ((size_t)143130624)    // 3 x bf16 [4096][1024]
#define OFF_W2T  ((size_t)168296448)    // 3 x bf16 [1024][4096]
#define OFF_HIDB OFF_K                  // bf16 [8192][4096] overlaps K,V,P (dead at CMS time)

__device__ __forceinline__ float b2f(ushort_t u) {
    return __uint_as_float(((unsigned int)u) << 16);
}
__device__ __forceinline__ ushort_t f2b(float f) {
    unsigned int u = __float_as_uint(f);
    u += 0x7FFFu + ((u >> 16) & 1u);          // round-to-nearest-even
    return (ushort_t)(u >> 16);
}
__device__ __forceinline__ void unpack4(uint2 u, float* f) {
    f[0] = __uint_as_float(u.x << 16);
    f[1] = __uint_as_float(u.x & 0xffff0000u);
    f[2] = __uint_as_float(u.y << 16);
    f[3] = __uint_as_float(u.y & 0xffff0000u);
}
// async 16B global->LDS DMA; LDS dest must be wave-uniform base + lane*16 [m97/m104]
__device__ __forceinline__ void ldg16(const ushort_t* g, ushort_t* l) {
    __builtin_amdgcn_global_load_lds(
        (const __attribute__((address_space(1))) void*)g,
        (__attribute__((address_space(3))) void*)l, 16, 0, 0);
}

// ---------------------------------------------------------------- transpose (f32 -> bf16)
__global__ void __launch_bounds__(256)
transpose_f32_bf16(const float* __restrict__ src, ushort_t* __restrict__ dst, int R, int C)
{
    __shared__ float t[32][33];
    const int bx = blockIdx.x * 32;
    const int by = blockIdx.y * 32;
    const int tx = threadIdx.x, ty = threadIdx.y;
    #pragma unroll
    for (int i = ty; i < 32; i += 8)
        t[i][tx] = src[(size_t)(by + i) * C + bx + tx];
    __syncthreads();
    #pragma unroll
    for (int i = ty; i < 32; i += 8)
        dst[(size_t)(bx + i) * R + by + tx] = f2b(t[tx][i]);
}

// ---------------------------------------------------------------- layernorm (f32 in, bf16 out)
__global__ void __launch_bounds__(256)
ln_fwd(const float* __restrict__ xin, const float* __restrict__ g,
       const float* __restrict__ be, ushort_t* __restrict__ out)
{
    const int row = blockIdx.x, tid = threadIdx.x;
    const float4 f = ((const float4*)(xin + (size_t)row * DIM))[tid];
    float v[4] = {f.x, f.y, f.z, f.w};
    float s  = v[0] + v[1] + v[2] + v[3];
    float ss = v[0]*v[0] + v[1]*v[1] + v[2]*v[2] + v[3]*v[3];
    #pragma unroll
    for (int off = 32; off; off >>= 1) {
        s  += __shfl_down(s, off);
        ss += __shfl_down(ss, off);
    }
    __shared__ float red[2][4];
    const int wave = tid >> 6, lane = tid & 63;
    if (lane == 0) { red[0][wave] = s; red[1][wave] = ss; }
    __syncthreads();
    s  = red[0][0] + red[0][1] + red[0][2] + red[0][3];
    ss = red[1][0] + red[1][1] + red[1][2] + red[1][3];
    const float mean = s * (1.0f / DIM);
    const float var  = ss * (1.0f / DIM) - mean * mean;
    const float rstd = rsqrtf(var + 1e-5f);
    ushort_t o[4];
    #pragma unroll
    for (int i = 0; i < 4; i++) {
        const int col = tid * 4 + i;
        o[i] = f2b((v[i] - mean) * rstd * g[col] + be[col]);
    }
    uint2 u2;
    u2.x = (unsigned int)o[0] | ((unsigned int)o[1] << 16);
    u2.y = (unsigned int)o[2] | ((unsigned int)o[3] << 16);
    *(uint2*)(out + (size_t)row * DIM + tid * 4) = u2;
}

// ---------------------------------------------------------------- GEMM (Bt), m97-style DMA staging
#define ACT_NONE 0
#define ACT_ELU1 1
#define ACT_GELU 2

template<int ACT, bool BIAS, bool RES, bool OUTF32>
__global__ void __launch_bounds__(256)
gemm_bt(const ushort_t* __restrict__ A, const ushort_t* __restrict__ Bt,
        const float* __restrict__ bias, const float* __restrict__ resid,
        void* __restrict__ Cout, int M, int N, int K)
{
    __shared__ __align__(16) ushort_t As[128 * 32];
    __shared__ __align__(16) ushort_t Bs[128 * 32];
    const int tid  = threadIdx.x;
    const int wave = tid >> 6, lane = tid & 63;
    const int bm = blockIdx.x * 128, bn = blockIdx.y * 128;
    const int wm = (wave >> 1) * 64, wn = (wave & 1) * 64;
    const int srow = tid >> 2;            // 0..63 staging row
    const int skp  = (tid & 3) * 8;       // 0,8,16,24 (elem offset in k)
    const int mrow = lane & 15, kq = (lane >> 4) * 8;

    f32x4 acc[4][4] = {};

    const size_t arow0 = (size_t)(bm + srow)      * K;
    const size_t arow1 = (size_t)(bm + srow + 64) * K;
    const size_t brow0 = (size_t)(bn + srow)      * K;
    const size_t brow1 = (size_t)(bn + srow + 64) * K;

    for (int kt = 0; kt < K; kt += 32) {
        __syncthreads();
        // LDS byte dest = 16*tid per slot: srow*32+skp == tid*8 elems  (wave-uniform + lane*16)
        ldg16(A  + arow0 + kt + skp, As + tid * 8);
        ldg16(A  + arow1 + kt + skp, As + 2048 + tid * 8);
        ldg16(Bt + brow0 + kt + skp, Bs + tid * 8);
        ldg16(Bt + brow1 + kt + skp, Bs + 2048 + tid * 8);
        __syncthreads();
        bf16x8 af[4], bfr[4];
        #pragma unroll
        for (int r = 0; r < 4; r++)
            af[r] = *(const bf16x8*)(As + (wm + r * 16 + mrow) * 32 + kq);
        #pragma unroll
        for (int c = 0; c < 4; c++)
            bfr[c] = *(const bf16x8*)(Bs + (wn + c * 16 + mrow) * 32 + kq);
        #pragma unroll
        for (int r = 0; r < 4; r++)
            #pragma unroll
            for (int c = 0; c < 4; c++)
                acc[r][c] = __builtin_amdgcn_mfma_f32_16x16x32_bf16(af[r], bfr[c], acc[r][c], 0, 0, 0);
    }

    // epilogue: C/D layout col=lane&15, row=(lane>>4)*4+reg   [m89/m91 verified]
    const int cr = (lane >> 4) * 4;
    const int cc = lane & 15;
    #pragma unroll
    for (int r = 0; r < 4; r++) {
        #pragma unroll
        for (int c = 0; c < 4; c++) {
            const int gc = bn + wn + c * 16 + cc;
            const float bv = BIAS ? bias[gc] : 0.0f;
            #pragma unroll
            for (int j = 0; j < 4; j++) {
                const int gr = bm + wm + r * 16 + cr + j;
                float vv = acc[r][c][j] + bv;
                if (ACT == ACT_ELU1) vv = (vv > 0.0f) ? (vv + 1.0f) : expf(vv);
                if (ACT == ACT_GELU) {
                    const float x3 = vv * vv * vv;
                    vv = 0.5f * vv * (1.0f + tanhf(0.7978845608028654f * (vv + 0.044715f * x3)));
                }
                const size_t oidx = (size_t)gr * N + gc;
                if (RES) vv += resid[oidx];
                if (OUTF32) ((float*)Cout)[oidx] = vv;
                else        ((ushort_t*)Cout)[oidx] = f2b(vv);
            }
        }
    }
}

// ---------------------------------------------------------------- attention
// phase 1: per chunk: M_c[d][e] = sum_t K[t,d]V[t,e]; ksum_c[d].  4x4 reg tiles.
__global__ void __launch_bounds__(256)
attn_phase1(const ushort_t* __restrict__ K_, const ushort_t* __restrict__ V_,
            float* __restrict__ P, float* __restrict__ Ksum)
{
    const int c = blockIdx.x, h = blockIdx.y, b = blockIdx.z;
    __shared__ ushort_t Ks[64][68], Vs[64][68];
    const int tid = threadIdx.x;
    const size_t rowbase = (size_t)b * SEQ + c * 64;
    #pragma unroll
    for (int i = 0; i < 4; i++) {
        const int lin = tid + 256 * i;          // (t, d4) over 64x16
        const int t = lin >> 4, d4 = (lin & 15) * 4;
        const size_t gidx = (rowbase + t) * DIM + h * HD + d4;
        *(uint2*)&Ks[t][d4] = *(const uint2*)(K_ + gidx);
        *(uint2*)&Vs[t][d4] = *(const uint2*)(V_ + gidx);
    }
    __syncthreads();
    const int d0 = (tid >> 4) * 4, e0 = (tid & 15) * 4;
    float acc[4][4] = {};
    for (int t = 0; t < 64; t++) {
        float kf[4], vf[4];
        unpack4(*(const uint2*)&Ks[t][d0], kf);
        unpack4(*(const uint2*)&Vs[t][e0], vf);
        #pragma unroll
        for (int i = 0; i < 4; i++)
            #pragma unroll
            for (int j = 0; j < 4; j++)
                acc[i][j] += kf[i] * vf[j];
    }
    const size_t pbase = (((size_t)b * NH + h) * NCHUNK + c) * 4096;
    #pragma unroll
    for (int i = 0; i < 4; i++) {
        float4 o; o.x = acc[i][0]; o.y = acc[i][1]; o.z = acc[i][2]; o.w = acc[i][3];
        *(float4*)(P + pbase + (size_t)(d0 + i) * 64 + e0) = o;
    }
    if (tid < 64) {
        float a = 0.0f;
        for (int t = 0; t < 64; t++) a += b2f(Ks[t][tid]);
        Ksum[(((size_t)b * NH + h) * NCHUNK + c) * 64 + tid] = a;
    }
}

// phase 1b: exclusive prefix over chunks, column-parallel.
__global__ void __launch_bounds__(256)
attn_prefix(float* __restrict__ P, float* __restrict__ Ksum)
{
    const int bh = blockIdx.y;
    const int e  = blockIdx.x * 256 + threadIdx.x;
    const size_t base = (size_t)bh * NCHUNK * 4096 + e;
    float acc = 0.0f;
    #pragma unroll
    for (int c = 0; c < NCHUNK; c++) {
        const float t = P[base + (size_t)c * 4096];
        P[base + (size_t)c * 4096] = acc;
        acc += t;
    }
    if (blockIdx.x == 0 && threadIdx.x < 64) {
        const size_t kb = (size_t)bh * NCHUNK * 64 + threadIdx.x;
        float a = 0.0f;
        #pragma unroll
        for (int c = 0; c < NCHUNK; c++) {
            const float t = Ksum[kb + c * 64];
            Ksum[kb + c * 64] = a;
            a += t;
        }
    }
}

// phase 2: out = (Q@M_prev + causal(QK^T)@V) / (Q@ksum_prev + rowsum(S) + 1e-6)
// 4x4 register micro-tiles; masked S entries stored as 0 -> branch-free SV loop.
// Out aliases Q_ (tile fully read to LDS before stores).
__global__ void __launch_bounds__(256)
attn_phase2(const ushort_t* Q_, const ushort_t* __restrict__ K_,
            const ushort_t* __restrict__ V_, const float* __restrict__ P,
            const float* __restrict__ Ksum, ushort_t* Out)
{
    const int c = blockIdx.x, h = blockIdx.y, b = blockIdx.z;
    const int tid = threadIdx.x;
    __shared__ ushort_t Qs[64][68], KsB[64][68], VsB[64][68];
    __shared__ float S[64][68];
    __shared__ float Mp[64][64];
    __shared__ float kp[64];
    __shared__ float partial[4][64];
    const size_t rowbase = (size_t)b * SEQ + c * 64;
    const size_t pbase = (((size_t)b * NH + h) * NCHUNK + c) * 4096;
    #pragma unroll
    for (int i = 0; i < 4; i++) {
        const int lin = tid + 256 * i;          // (t, d4) over 64x16
        const int t = lin >> 4, d4 = (lin & 15) * 4;
        const size_t gidx = (rowbase + t) * DIM + h * HD + d4;
        *(uint2*)&Qs[t][d4]  = *(const uint2*)(Q_ + gidx);
        *(uint2*)&KsB[t][d4] = *(const uint2*)(K_ + gidx);
        *(uint2*)&VsB[t][d4] = *(const uint2*)(V_ + gidx);
        *(float4*)&Mp[t][d4] = *(const float4*)(P + pbase + lin * 4);
    }
    if (tid < 64) kp[tid] = Ksum[(((size_t)b * NH + h) * NCHUNK + c) * 64 + tid];
    __syncthreads();

    const int t0 = (tid >> 4) * 4;
    const int c0 = (tid & 15) * 4;              // ii-block for S phase, e-block later

    // S = causal(Q K^T); masked entries written as 0
    {
        float accS[4][4] = {};
        for (int d4 = 0; d4 < 64; d4 += 4) {
            float qf[4][4], kf[4][4];
            #pragma unroll
            for (int i = 0; i < 4; i++) {
                unpack4(*(const uint2*)&Qs[t0 + i][d4], qf[i]);
                unpack4(*(const uint2*)&KsB[c0 + i][d4], kf[i]);
            }
            #pragma unroll
            for (int i = 0; i < 4; i++)
                #pragma unroll
                for (int j = 0; j < 4; j++)
                    #pragma unroll
                    for (int dd = 0; dd < 4; dd++)
                        accS[i][j] += qf[i][dd] * kf[j][dd];
        }
        #pragma unroll
        for (int i = 0; i < 4; i++) {
            float4 sv;
            sv.x = (c0 + 0 <= t0 + i) ? accS[i][0] : 0.0f;
            sv.y = (c0 + 1 <= t0 + i) ? accS[i][1] : 0.0f;
            sv.z = (c0 + 2 <= t0 + i) ? accS[i][2] : 0.0f;
            sv.w = (c0 + 3 <= t0 + i) ? accS[i][3] : 0.0f;
            *(float4*)&S[t0 + i][c0] = sv;
        }
    }
    __syncthreads();

    // den partials: quarter-range per thread
    {
        const int t = tid & 63, q = tid >> 6;
        const int base = q * 16;
        float a = 0.0f;
        #pragma unroll
        for (int ii = 0; ii < 16; ii++) a += S[t][base + ii];
        #pragma unroll
        for (int d = 0; d < 16; d++) a += b2f(Qs[t][base + d]) * kp[base + d];
        partial[q][t] = a;
    }
    __syncthreads();

    // out = S@V + Q@Mp, then /den
    float acc[4][4] = {};
    for (int ii = 0; ii < 64; ii++) {
        float vf[4];
        unpack4(*(const uint2*)&VsB[ii][c0], vf);
        #pragma unroll
        for (int i = 0; i < 4; i++) {
            const float s = S[t0 + i][ii];
            #pragma unroll
            for (int j = 0; j < 4; j++) acc[i][j] += s * vf[j];
        }
    }
    for (int d = 0; d < 64; d++) {
        const float4 mp = *(const float4*)&Mp[d][c0];
        #pragma unroll
        for (int i = 0; i < 4; i++) {
            const float qv = b2f(Qs[t0 + i][d]);
            acc[i][0] += qv * mp.x; acc[i][1] += qv * mp.y;
            acc[i][2] += qv * mp.z; acc[i][3] += qv * mp.w;
        }
    }
    #pragma unroll
    for (int i = 0; i < 4; i++) {
        const float dent = partial[0][t0 + i] + partial[1][t0 + i] +
                           partial[2][t0 + i] + partial[3][t0 + i] + 1e-6f;
        const float r = 1.0f / dent;
        ushort_t o[4];
        #pragma unroll
        for (int j = 0; j < 4; j++) o[j] = f2b(acc[i][j] * r);
        uint2 u2;
        u2.x = (unsigned int)o[0] | ((unsigned int)o[1] << 16);
        u2.y = (unsigned int)o[2] | ((unsigned int)o[3] << 16);
        *(uint2*)(Out + (rowbase + t0 + i) * DIM + h * HD + c0) = u2;
    }
}

// ---------------------------------------------------------------- launcher
extern "C" void kernel_launch(void* const* d_in, const int* in_sizes, int n_in,
                              void* d_out, int out_size, void* d_ws, size_t ws_size,
                              hipStream_t stream)
{
    const float* x      = (const float*)d_in[0];
    const float* Wq     = (const float*)d_in[1];
    const float* Wk     = (const float*)d_in[2];
    const float* Wv     = (const float*)d_in[3];
    const float* Wo     = (const float*)d_in[4];
    const float* ln1g   = (const float*)d_in[5];
    const float* ln1b   = (const float*)d_in[6];
    const float* ln2g   = (const float*)d_in[7];
    const float* ln2b   = (const float*)d_in[8];
    const float* cw1    = (const float*)d_in[9];
    const float* cb1    = (const float*)d_in[10];
    const float* cw2    = (const float*)d_in[11];
    const float* cb2    = (const float*)d_in[12];

    char* ws = (char*)d_ws;
    ushort_t* h    = (ushort_t*)(ws + OFF_H);
    ushort_t* qb   = (ushort_t*)(ws + OFF_Q);
    ushort_t* kb   = (ushort_t*)(ws + OFF_K);
    ushort_t* vb   = (ushort_t*)(ws + OFF_V);
    float*    Pb   = (float*)(ws + OFF_P);
    float*    ksb  = (float*)(ws + OFF_KS);
    float*    x1   = (float*)(ws + OFF_X1);
    ushort_t* wqt  = (ushort_t*)(ws + OFF_WQT);
    ushort_t* wkt  = (ushort_t*)(ws + OFF_WKT);
    ushort_t* wvt  = (ushort_t*)(ws + OFF_WVT);
    ushort_t* wot  = (ushort_t*)(ws + OFF_WOT);
    ushort_t* w1t  = (ushort_t*)(ws + OFF_W1T);
    ushort_t* w2t  = (ushort_t*)(ws + OFF_W2T);
    ushort_t* hid  = (ushort_t*)(ws + OFF_HIDB);
    float*    outp = (float*)d_out;

    const dim3 tb(32, 8);
    transpose_f32_bf16<<<dim3(32, 32), tb, 0, stream>>>(Wq, wqt, DIM, DIM);
    transpose_f32_bf16<<<dim3(32, 32), tb, 0, stream>>>(Wk, wkt, DIM, DIM);
    transpose_f32_bf16<<<dim3(32, 32), tb, 0, stream>>>(Wv, wvt, DIM, DIM);
    transpose_f32_bf16<<<dim3(32, 32), tb, 0, stream>>>(Wo, wot, DIM, DIM);
    for (int l = 0; l < 3; l++) {
        transpose_f32_bf16<<<dim3(128, 32), tb, 0, stream>>>(cw1 + (size_t)l * DIM * HID,
                                                             w1t + (size_t)l * HID * DIM, DIM, HID);
        transpose_f32_bf16<<<dim3(32, 128), tb, 0, stream>>>(cw2 + (size_t)l * HID * DIM,
                                                             w2t + (size_t)l * DIM * HID, HID, DIM);
    }

    ln_fwd<<<MROWS, 256, 0, stream>>>(x, ln1g, ln1b, h);

    gemm_bt<ACT_ELU1, false, false, false><<<dim3(64, 8), 256, 0, stream>>>(h, wqt, nullptr, nullptr, qb, MROWS, DIM, DIM);
    gemm_bt<ACT_ELU1, false, false, false><<<dim3(64, 8), 256, 0, stream>>>(h, wkt, nullptr, nullptr, kb, MROWS, DIM, DIM);
    gemm_bt<ACT_NONE, false, false, false><<<dim3(64, 8), 256, 0, stream>>>(h, wvt, nullptr, nullptr, vb, MROWS, DIM, DIM);

    attn_phase1<<<dim3(NCHUNK, NH, NB), 256, 0, stream>>>(kb, vb, Pb, ksb);
    attn_prefix<<<dim3(16, 64), 256, 0, stream>>>(Pb, ksb);
    attn_phase2<<<dim3(NCHUNK, NH, NB), 256, 0, stream>>>(qb, kb, vb, Pb, ksb, qb);

    gemm_bt<ACT_NONE, false, true, true><<<dim3(64, 8), 256, 0, stream>>>(qb, wot, nullptr, x, x1, MROWS, DIM, DIM);

    ln_fwd<<<MROWS, 256, 0, stream>>>(x1, ln2g, ln2b, h);

    const ushort_t* cur = h;
    for (int l = 0; l < 3; l++) {
        gemm_bt<ACT_GELU, true, false, false><<<dim3(64, 32), 256, 0, stream>>>(
            cur, w1t + (size_t)l * HID * DIM, cb1 + (size_t)l * HID, nullptr, hid, MROWS, HID, DIM);
        if (l < 2) {
            gemm_bt<ACT_NONE, true, false, false><<<dim3(64, 8), 256, 0, stream>>>(
                hid, w2t + (size_t)l * DIM * HID, cb2 + (size_t)l * DIM, nullptr, h, MROWS, DIM, HID);
            cur = h;
        } else {
            gemm_bt<ACT_NONE, true, true, true><<<dim3(64, 8), 256, 0, stream>>>(
                hid, w2t + (size_t)l * DIM * HID, cb2 + (size_t)l * DIM, x1, outp, MROWS, DIM, HID);
        }
    }
    (void)in_sizes; (void)n_in; (void)out_size; (void)ws_size;
}

// Round 4
// 1047.497 us; speedup vs baseline: 1.1891x; 1.0002x over previous
//
#include <hip/hip_runtime.h>
#include <stdint.h>
#include <math.h>

// ---------------------------------------------------------------- constants
#define DIM     1024
#define HID     4096
#define SEQ     2048
#define NB      4
#define NH      16
#define HD      64
#define NCHUNK  32          // SEQ / 64
#define MROWS   8192        // NB * SEQ
#define QSTR    3072        // fused qkv row stride

typedef unsigned short ushort_t;
typedef __attribute__((ext_vector_type(8))) short bf16x8;
typedef __attribute__((ext_vector_type(4))) float f32x4;

// ws layout (bytes) — peak ~193.5 MB, proven non-faulting
#define OFF_H    ((size_t)0)            // bf16 [8192][1024]
#define OFF_Q    ((size_t)16777216)     // bf16 [8192][3072] fused qkv (spans old Q,K,V)
#define OFF_P    ((size_t)67108864)     // f32 [64][32][4096]
#define OFF_KS   ((size_t)100663296)    // f32 [64][32][64]
#define OFF_X1   ((size_t)101187584)    // f32 [8192][1024]
#define OFF_WQT  ((size_t)134742016)    // bf16 [3072][1024] fused qkv weights^T
#define OFF_WOT  ((size_t)141033472)
#define OFF_W1T  ((size_t)143130624)    // 3 x bf16 [4096][1024]
#define OFF_W2T  ((size_t)168296448)    // 3 x bf16 [1024][4096]
#define OFF_HIDB OFF_Q + 16777216       // bf16 [8192][4096]: spans old K,V,P (dead at CMS time)

__device__ __forceinline__ float b2f(ushort_t u) {
    return __uint_as_float(((unsigned int)u) << 16);
}
__device__ __forceinline__ ushort_t f2b(float f) {
    unsigned int u = __float_as_uint(f);
    u += 0x7FFFu + ((u >> 16) & 1u);          // round-to-nearest-even
    return (ushort_t)(u >> 16);
}
__device__ __forceinline__ void unpack4(uint2 u, float* f) {
    f[0] = __uint_as_float(u.x << 16);
    f[1] = __uint_as_float(u.x & 0xffff0000u);
    f[2] = __uint_as_float(u.y << 16);
    f[3] = __uint_as_float(u.y & 0xffff0000u);
}
// gelu(tanh form) == x*sigmoid(2z); ~7 VALU ops vs ~40 for libm tanhf
__device__ __forceinline__ float fast_gelu(float x) {
    const float u = x * (1.5957691216057308f + 0.07135481627f * x * x);  // 2z
    const float e = exp2f(-1.4426950408889634f * u);
    return x * __builtin_amdgcn_rcpf(1.0f + e);
}
__device__ __forceinline__ float fast_elu1(float x) {
    return x > 0.0f ? x + 1.0f : exp2f(1.4426950408889634f * x);
}
// async 16B global->LDS DMA; LDS dest must be wave-uniform base + lane*16 [m97/m104]
__device__ __forceinline__ void ldg16(const ushort_t* g, ushort_t* l) {
    __builtin_amdgcn_global_load_lds(
        (const __attribute__((address_space(1))) void*)g,
        (__attribute__((address_space(3))) void*)l, 16, 0, 0);
}

// ---------------------------------------------------------------- transpose (f32 -> bf16)
__global__ void __launch_bounds__(256)
transpose_f32_bf16(const float* __restrict__ src, ushort_t* __restrict__ dst, int R, int C)
{
    __shared__ float t[32][33];
    const int bx = blockIdx.x * 32;
    const int by = blockIdx.y * 32;
    const int tx = threadIdx.x, ty = threadIdx.y;
    #pragma unroll
    for (int i = ty; i < 32; i += 8)
        t[i][tx] = src[(size_t)(by + i) * C + bx + tx];
    __syncthreads();
    #pragma unroll
    for (int i = ty; i < 32; i += 8)
        dst[(size_t)(bx + i) * R + by + tx] = f2b(t[tx][i]);
}

// ---------------------------------------------------------------- layernorm (f32 in, bf16 out)
__global__ void __launch_bounds__(256)
ln_fwd(const float* __restrict__ xin, const float* __restrict__ g,
       const float* __restrict__ be, ushort_t* __restrict__ out)
{
    const int row = blockIdx.x, tid = threadIdx.x;
    const float4 f = ((const float4*)(xin + (size_t)row * DIM))[tid];
    float v[4] = {f.x, f.y, f.z, f.w};
    float s  = v[0] + v[1] + v[2] + v[3];
    float ss = v[0]*v[0] + v[1]*v[1] + v[2]*v[2] + v[3]*v[3];
    #pragma unroll
    for (int off = 32; off; off >>= 1) {
        s  += __shfl_down(s, off);
        ss += __shfl_down(ss, off);
    }
    __shared__ float red[2][4];
    const int wave = tid >> 6, lane = tid & 63;
    if (lane == 0) { red[0][wave] = s; red[1][wave] = ss; }
    __syncthreads();
    s  = red[0][0] + red[0][1] + red[0][2] + red[0][3];
    ss = red[1][0] + red[1][1] + red[1][2] + red[1][3];
    const float mean = s * (1.0f / DIM);
    const float var  = ss * (1.0f / DIM) - mean * mean;
    const float rstd = rsqrtf(var + 1e-5f);
    ushort_t o[4];
    #pragma unroll
    for (int i = 0; i < 4; i++) {
        const int col = tid * 4 + i;
        o[i] = f2b((v[i] - mean) * rstd * g[col] + be[col]);
    }
    uint2 u2;
    u2.x = (unsigned int)o[0] | ((unsigned int)o[1] << 16);
    u2.y = (unsigned int)o[2] | ((unsigned int)o[3] << 16);
    *(uint2*)(out + (size_t)row * DIM + tid * 4) = u2;
}

// ---------------------------------------------------------------- GEMM (Bt), m97-style DMA staging
#define ACT_NONE 0
#define ACT_ELU1 1
#define ACT_GELU 2
#define ACT_QKV  3   // cols < 2048 -> elu+1 (Q,K); cols >= 2048 -> none (V). block-uniform.

template<int ACT, bool BIAS, bool RES, bool OUTF32>
__global__ void __launch_bounds__(256)
gemm_bt(const ushort_t* __restrict__ A, const ushort_t* __restrict__ Bt,
        const float* __restrict__ bias, const float* __restrict__ resid,
        void* __restrict__ Cout, int M, int N, int K)
{
    __shared__ __align__(16) ushort_t As[128 * 32];
    __shared__ __align__(16) ushort_t Bs[128 * 32];
    const int tid  = threadIdx.x;
    const int wave = tid >> 6, lane = tid & 63;
    const int bm = blockIdx.x * 128, bn = blockIdx.y * 128;
    const int wm = (wave >> 1) * 64, wn = (wave & 1) * 64;
    const int srow = tid >> 2;            // 0..63 staging row
    const int skp  = (tid & 3) * 8;       // 0,8,16,24 (elem offset in k)
    const int mrow = lane & 15, kq = (lane >> 4) * 8;
    const bool qkv_elu = (bn < 2048);     // wave-uniform (128 | 2048)

    f32x4 acc[4][4] = {};

    const size_t arow0 = (size_t)(bm + srow)      * K;
    const size_t arow1 = (size_t)(bm + srow + 64) * K;
    const size_t brow0 = (size_t)(bn + srow)      * K;
    const size_t brow1 = (size_t)(bn + srow + 64) * K;

    for (int kt = 0; kt < K; kt += 32) {
        __syncthreads();
        // LDS byte dest = 16*tid per slot (wave-uniform base + lane*16)
        ldg16(A  + arow0 + kt + skp, As + tid * 8);
        ldg16(A  + arow1 + kt + skp, As + 2048 + tid * 8);
        ldg16(Bt + brow0 + kt + skp, Bs + tid * 8);
        ldg16(Bt + brow1 + kt + skp, Bs + 2048 + tid * 8);
        __syncthreads();
        bf16x8 af[4], bfr[4];
        #pragma unroll
        for (int r = 0; r < 4; r++)
            af[r] = *(const bf16x8*)(As + (wm + r * 16 + mrow) * 32 + kq);
        #pragma unroll
        for (int c = 0; c < 4; c++)
            bfr[c] = *(const bf16x8*)(Bs + (wn + c * 16 + mrow) * 32 + kq);
        #pragma unroll
        for (int r = 0; r < 4; r++)
            #pragma unroll
            for (int c = 0; c < 4; c++)
                acc[r][c] = __builtin_amdgcn_mfma_f32_16x16x32_bf16(af[r], bfr[c], acc[r][c], 0, 0, 0);
    }

    // epilogue: C/D layout col=lane&15, row=(lane>>4)*4+reg   [m89/m91 verified]
    const int cr = (lane >> 4) * 4;
    const int cc = lane & 15;
    #pragma unroll
    for (int r = 0; r < 4; r++) {
        #pragma unroll
        for (int c = 0; c < 4; c++) {
            const int gc = bn + wn + c * 16 + cc;
            const float bv = BIAS ? bias[gc] : 0.0f;
            #pragma unroll
            for (int j = 0; j < 4; j++) {
                const int gr = bm + wm + r * 16 + cr + j;
                float vv = acc[r][c][j] + bv;
                if (ACT == ACT_ELU1) vv = fast_elu1(vv);
                if (ACT == ACT_GELU) vv = fast_gelu(vv);
                if (ACT == ACT_QKV)  vv = qkv_elu ? fast_elu1(vv) : vv;
                const size_t oidx = (size_t)gr * N + gc;
                if (RES) vv += resid[oidx];
                if (OUTF32) ((float*)Cout)[oidx] = vv;
                else        ((ushort_t*)Cout)[oidx] = f2b(vv);
            }
        }
    }
}

// ---------------------------------------------------------------- attention
// qkv buffer row stride = QSTR; K at col 1024, V at col 2048
// phase 1: per chunk: M_c[d][e] = sum_t K[t,d]V[t,e]; ksum_c[d].  4x4 reg tiles.
__global__ void __launch_bounds__(256)
attn_phase1(const ushort_t* __restrict__ qkv,
            float* __restrict__ P, float* __restrict__ Ksum)
{
    const int c = blockIdx.x, h = blockIdx.y, b = blockIdx.z;
    __shared__ ushort_t Ks[64][68], Vs[64][68];
    const int tid = threadIdx.x;
    const size_t rowbase = (size_t)b * SEQ + c * 64;
    #pragma unroll
    for (int i = 0; i < 4; i++) {
        const int lin = tid + 256 * i;          // (t, d4) over 64x16
        const int t = lin >> 4, d4 = (lin & 15) * 4;
        const size_t gidx = (rowbase + t) * QSTR + h * HD + d4;
        *(uint2*)&Ks[t][d4] = *(const uint2*)(qkv + 1024 + gidx);
        *(uint2*)&Vs[t][d4] = *(const uint2*)(qkv + 2048 + gidx);
    }
    __syncthreads();
    const int d0 = (tid >> 4) * 4, e0 = (tid & 15) * 4;
    float acc[4][4] = {};
    for (int t = 0; t < 64; t++) {
        float kf[4], vf[4];
        unpack4(*(const uint2*)&Ks[t][d0], kf);
        unpack4(*(const uint2*)&Vs[t][e0], vf);
        #pragma unroll
        for (int i = 0; i < 4; i++)
            #pragma unroll
            for (int j = 0; j < 4; j++)
                acc[i][j] += kf[i] * vf[j];
    }
    const size_t pbase = (((size_t)b * NH + h) * NCHUNK + c) * 4096;
    #pragma unroll
    for (int i = 0; i < 4; i++) {
        float4 o; o.x = acc[i][0]; o.y = acc[i][1]; o.z = acc[i][2]; o.w = acc[i][3];
        *(float4*)(P + pbase + (size_t)(d0 + i) * 64 + e0) = o;
    }
    if (tid < 64) {
        float a = 0.0f;
        for (int t = 0; t < 64; t++) a += b2f(Ks[t][tid]);
        Ksum[(((size_t)b * NH + h) * NCHUNK + c) * 64 + tid] = a;
    }
}

// phase 1b: exclusive prefix over chunks, column-parallel.
__global__ void __launch_bounds__(256)
attn_prefix(float* __restrict__ P, float* __restrict__ Ksum)
{
    const int bh = blockIdx.y;
    const int e  = blockIdx.x * 256 + threadIdx.x;
    const size_t base = (size_t)bh * NCHUNK * 4096 + e;
    float acc = 0.0f;
    #pragma unroll
    for (int c = 0; c < NCHUNK; c++) {
        const float t = P[base + (size_t)c * 4096];
        P[base + (size_t)c * 4096] = acc;
        acc += t;
    }
    if (blockIdx.x == 0 && threadIdx.x < 64) {
        const size_t kb = (size_t)bh * NCHUNK * 64 + threadIdx.x;
        float a = 0.0f;
        #pragma unroll
        for (int c = 0; c < NCHUNK; c++) {
            const float t = Ksum[kb + c * 64];
            Ksum[kb + c * 64] = a;
            a += t;
        }
    }
}

// phase 2: out = (Q@M_prev + causal(QK^T)@V) / (Q@ksum_prev + rowsum(S) + 1e-6)
// reads fused qkv (stride QSTR), writes contiguous [MROWS][DIM] output
__global__ void __launch_bounds__(256)
attn_phase2(const ushort_t* __restrict__ qkv, const float* __restrict__ P,
            const float* __restrict__ Ksum, ushort_t* __restrict__ Out)
{
    const int c = blockIdx.x, h = blockIdx.y, b = blockIdx.z;
    const int tid = threadIdx.x;
    __shared__ ushort_t Qs[64][68], KsB[64][68], VsB[64][68];
    __shared__ float S[64][68];
    __shared__ float Mp[64][64];
    __shared__ float kp[64];
    __shared__ float partial[4][64];
    const size_t rowbase = (size_t)b * SEQ + c * 64;
    const size_t pbase = (((size_t)b * NH + h) * NCHUNK + c) * 4096;
    #pragma unroll
    for (int i = 0; i < 4; i++) {
        const int lin = tid + 256 * i;          // (t, d4) over 64x16
        const int t = lin >> 4, d4 = (lin & 15) * 4;
        const size_t gidx = (rowbase + t) * QSTR + h * HD + d4;
        *(uint2*)&Qs[t][d4]  = *(const uint2*)(qkv + gidx);
        *(uint2*)&KsB[t][d4] = *(const uint2*)(qkv + 1024 + gidx);
        *(uint2*)&VsB[t][d4] = *(const uint2*)(qkv + 2048 + gidx);
        *(float4*)&Mp[t][d4] = *(const float4*)(P + pbase + lin * 4);
    }
    if (tid < 64) kp[tid] = Ksum[(((size_t)b * NH + h) * NCHUNK + c) * 64 + tid];
    __syncthreads();

    const int t0 = (tid >> 4) * 4;
    const int c0 = (tid & 15) * 4;              // ii-block for S phase, e-block later

    // S = causal(Q K^T); masked entries written as 0
    {
        float accS[4][4] = {};
        for (int d4 = 0; d4 < 64; d4 += 4) {
            float qf[4][4], kf[4][4];
            #pragma unroll
            for (int i = 0; i < 4; i++) {
                unpack4(*(const uint2*)&Qs[t0 + i][d4], qf[i]);
                unpack4(*(const uint2*)&KsB[c0 + i][d4], kf[i]);
            }
            #pragma unroll
            for (int i = 0; i < 4; i++)
                #pragma unroll
                for (int j = 0; j < 4; j++)
                    #pragma unroll
                    for (int dd = 0; dd < 4; dd++)
                        accS[i][j] += qf[i][dd] * kf[j][dd];
        }
        #pragma unroll
        for (int i = 0; i < 4; i++) {
            float4 sv;
            sv.x = (c0 + 0 <= t0 + i) ? accS[i][0] : 0.0f;
            sv.y = (c0 + 1 <= t0 + i) ? accS[i][1] : 0.0f;
            sv.z = (c0 + 2 <= t0 + i) ? accS[i][2] : 0.0f;
            sv.w = (c0 + 3 <= t0 + i) ? accS[i][3] : 0.0f;
            *(float4*)&S[t0 + i][c0] = sv;
        }
    }
    __syncthreads();

    // den partials: quarter-range per thread
    {
        const int t = tid & 63, q = tid >> 6;
        const int base = q * 16;
        float a = 0.0f;
        #pragma unroll
        for (int ii = 0; ii < 16; ii++) a += S[t][base + ii];
        #pragma unroll
        for (int d = 0; d < 16; d++) a += b2f(Qs[t][base + d]) * kp[base + d];
        partial[q][t] = a;
    }
    __syncthreads();

    // out = S@V + Q@Mp, then /den
    float acc[4][4] = {};
    for (int ii = 0; ii < 64; ii++) {
        float vf[4];
        unpack4(*(const uint2*)&VsB[ii][c0], vf);
        #pragma unroll
        for (int i = 0; i < 4; i++) {
            const float s = S[t0 + i][ii];
            #pragma unroll
            for (int j = 0; j < 4; j++) acc[i][j] += s * vf[j];
        }
    }
    for (int d = 0; d < 64; d++) {
        const float4 mp = *(const float4*)&Mp[d][c0];
        #pragma unroll
        for (int i = 0; i < 4; i++) {
            const float qv = b2f(Qs[t0 + i][d]);
            acc[i][0] += qv * mp.x; acc[i][1] += qv * mp.y;
            acc[i][2] += qv * mp.z; acc[i][3] += qv * mp.w;
        }
    }
    #pragma unroll
    for (int i = 0; i < 4; i++) {
        const float dent = partial[0][t0 + i] + partial[1][t0 + i] +
                           partial[2][t0 + i] + partial[3][t0 + i] + 1e-6f;
        const float r = 1.0f / dent;
        ushort_t o[4];
        #pragma unroll
        for (int j = 0; j < 4; j++) o[j] = f2b(acc[i][j] * r);
        uint2 u2;
        u2.x = (unsigned int)o[0] | ((unsigned int)o[1] << 16);
        u2.y = (unsigned int)o[2] | ((unsigned int)o[3] << 16);
        *(uint2*)(Out + (rowbase + t0 + i) * DIM + h * HD + c0) = u2;
    }
}

// ---------------------------------------------------------------- launcher
extern "C" void kernel_launch(void* const* d_in, const int* in_sizes, int n_in,
                              void* d_out, int out_size, void* d_ws, size_t ws_size,
                              hipStream_t stream)
{
    const float* x      = (const float*)d_in[0];
    const float* Wq     = (const float*)d_in[1];
    const float* Wk     = (const float*)d_in[2];
    const float* Wv     = (const float*)d_in[3];
    const float* Wo     = (const float*)d_in[4];
    const float* ln1g   = (const float*)d_in[5];
    const float* ln1b   = (const float*)d_in[6];
    const float* ln2g   = (const float*)d_in[7];
    const float* ln2b   = (const float*)d_in[8];
    const float* cw1    = (const float*)d_in[9];
    const float* cb1    = (const float*)d_in[10];
    const float* cw2    = (const float*)d_in[11];
    const float* cb2    = (const float*)d_in[12];

    char* ws = (char*)d_ws;
    ushort_t* h     = (ushort_t*)(ws + OFF_H);
    ushort_t* qkv   = (ushort_t*)(ws + OFF_Q);
    float*    Pb    = (float*)(ws + OFF_P);
    float*    ksb   = (float*)(ws + OFF_KS);
    float*    x1    = (float*)(ws + OFF_X1);
    ushort_t* wqkvt = (ushort_t*)(ws + OFF_WQT);
    ushort_t* wot   = (ushort_t*)(ws + OFF_WOT);
    ushort_t* w1t   = (ushort_t*)(ws + OFF_W1T);
    ushort_t* w2t   = (ushort_t*)(ws + OFF_W2T);
    ushort_t* hid   = (ushort_t*)(ws + OFF_HIDB);
    float*    outp  = (float*)d_out;

    const dim3 tb(32, 8);
    // fused qkv weight^T: [3072][1024]
    transpose_f32_bf16<<<dim3(32, 32), tb, 0, stream>>>(Wq, wqkvt,                   DIM, DIM);
    transpose_f32_bf16<<<dim3(32, 32), tb, 0, stream>>>(Wk, wqkvt + 1024 * 1024,     DIM, DIM);
    transpose_f32_bf16<<<dim3(32, 32), tb, 0, stream>>>(Wv, wqkvt + 2 * 1024 * 1024, DIM, DIM);
    transpose_f32_bf16<<<dim3(32, 32), tb, 0, stream>>>(Wo, wot, DIM, DIM);
    for (int l = 0; l < 3; l++) {
        transpose_f32_bf16<<<dim3(128, 32), tb, 0, stream>>>(cw1 + (size_t)l * DIM * HID,
                                                             w1t + (size_t)l * HID * DIM, DIM, HID);
        transpose_f32_bf16<<<dim3(32, 128), tb, 0, stream>>>(cw2 + (size_t)l * HID * DIM,
                                                             w2t + (size_t)l * DIM * HID, HID, DIM);
    }

    ln_fwd<<<MROWS, 256, 0, stream>>>(x, ln1g, ln1b, h);

    // fused Q|K|V projection: [8192][3072], elu+1 on first 2048 cols
    gemm_bt<ACT_QKV, false, false, false><<<dim3(64, 24), 256, 0, stream>>>(
        h, wqkvt, nullptr, nullptr, qkv, MROWS, QSTR, DIM);

    attn_phase1<<<dim3(NCHUNK, NH, NB), 256, 0, stream>>>(qkv, Pb, ksb);
    attn_prefix<<<dim3(16, 64), 256, 0, stream>>>(Pb, ksb);
    attn_phase2<<<dim3(NCHUNK, NH, NB), 256, 0, stream>>>(qkv, Pb, ksb, h);  // h := attn out

    gemm_bt<ACT_NONE, false, true, true><<<dim3(64, 8), 256, 0, stream>>>(h, wot, nullptr, x, x1, MROWS, DIM, DIM);

    ln_fwd<<<MROWS, 256, 0, stream>>>(x1, ln2g, ln2b, h);

    const ushort_t* cur = h;
    for (int l = 0; l < 3; l++) {
        gemm_bt<ACT_GELU, true, false, false><<<dim3(64, 32), 256, 0, stream>>>(
            cur, w1t + (size_t)l * HID * DIM, cb1 + (size_t)l * HID, nullptr, hid, MROWS, HID, DIM);
        if (l < 2) {
            gemm_bt<ACT_NONE, true, false, false><<<dim3(64, 8), 256, 0, stream>>>(
                hid, w2t + (size_t)l * DIM * HID, cb2 + (size_t)l * DIM, nullptr, h, MROWS, DIM, HID);
            cur = h;
        } else {
            gemm_bt<ACT_NONE, true, true, true><<<dim3(64, 8), 256, 0, stream>>>(
                hid, w2t + (size_t)l * DIM * HID, cb2 + (size_t)l * DIM, x1, outp, MROWS, DIM, HID);
        }
    }
    (void)in_sizes; (void)n_in; (void)out_size; (void)ws_size;
}

// Round 5
// 894.509 us; speedup vs baseline: 1.3924x; 1.1710x over previous
//
#include <hip/hip_runtime.h>
#include <stdint.h>
#include <math.h>

// ---------------------------------------------------------------- constants
#define DIM     1024
#define HID     4096
#define SEQ     2048
#define NB      4
#define NH      16
#define HD      64
#define NCHUNK  32          // SEQ / 64
#define MROWS   8192        // NB * SEQ
#define QSTR    3072        // fused qkv row stride

typedef unsigned short ushort_t;
typedef __attribute__((ext_vector_type(8))) short bf16x8;
typedef __attribute__((ext_vector_type(4))) float f32x4;

// ws layout (bytes) — peak ~193.5 MB, proven non-faulting
#define OFF_H    ((size_t)0)            // bf16 [8192][1024]
#define OFF_Q    ((size_t)16777216)     // bf16 [8192][3072] fused qkv
#define OFF_P    ((size_t)67108864)     // f32 [64][32][4096]
#define OFF_KS   ((size_t)100663296)    // f32 [64][32][64]
#define OFF_X1   ((size_t)101187584)    // f32 [8192][1024]
#define OFF_WQT  ((size_t)134742016)    // bf16 [3072][1024] fused qkv weights^T
#define OFF_WOT  ((size_t)141033472)
#define OFF_W1T  ((size_t)143130624)    // 3 x bf16 [4096][1024]
#define OFF_W2T  ((size_t)168296448)    // 3 x bf16 [1024][4096]
#define OFF_HIDB OFF_Q + 16777216       // bf16 [8192][4096]: spans old K,V,P (dead at CMS time)

__device__ __forceinline__ float b2f(ushort_t u) {
    return __uint_as_float(((unsigned int)u) << 16);
}
__device__ __forceinline__ ushort_t f2b(float f) {
    unsigned int u = __float_as_uint(f);
    u += 0x7FFFu + ((u >> 16) & 1u);          // round-to-nearest-even
    return (ushort_t)(u >> 16);
}
__device__ __forceinline__ void unpack4(uint2 u, float* f) {
    f[0] = __uint_as_float(u.x << 16);
    f[1] = __uint_as_float(u.x & 0xffff0000u);
    f[2] = __uint_as_float(u.y << 16);
    f[3] = __uint_as_float(u.y & 0xffff0000u);
}
// gelu(tanh form) == x*sigmoid(2z); ~7 VALU ops vs ~40 for libm tanhf
__device__ __forceinline__ float fast_gelu(float x) {
    const float u = x * (1.5957691216057308f + 0.07135481627f * x * x);  // 2z
    const float e = exp2f(-1.4426950408889634f * u);
    return x * __builtin_amdgcn_rcpf(1.0f + e);
}
__device__ __forceinline__ float fast_elu1(float x) {
    return x > 0.0f ? x + 1.0f : exp2f(1.4426950408889634f * x);
}
// async 16B global->LDS DMA; LDS dest must be wave-uniform base + lane*16 [m97/m104]
__device__ __forceinline__ void ldg16(const ushort_t* g, ushort_t* l) {
    __builtin_amdgcn_global_load_lds(
        (const __attribute__((address_space(1))) void*)g,
        (__attribute__((address_space(3))) void*)l, 16, 0, 0);
}

// ---------------------------------------------------------------- transpose (f32 -> bf16)
__global__ void __launch_bounds__(256)
transpose_f32_bf16(const float* __restrict__ src, ushort_t* __restrict__ dst, int R, int C)
{
    __shared__ float t[32][33];
    const int bx = blockIdx.x * 32;
    const int by = blockIdx.y * 32;
    const int tx = threadIdx.x, ty = threadIdx.y;
    #pragma unroll
    for (int i = ty; i < 32; i += 8)
        t[i][tx] = src[(size_t)(by + i) * C + bx + tx];
    __syncthreads();
    #pragma unroll
    for (int i = ty; i < 32; i += 8)
        dst[(size_t)(bx + i) * R + by + tx] = f2b(t[tx][i]);
}

// ---------------------------------------------------------------- layernorm (f32 in, bf16 out)
__global__ void __launch_bounds__(256)
ln_fwd(const float* __restrict__ xin, const float* __restrict__ g,
       const float* __restrict__ be, ushort_t* __restrict__ out)
{
    const int row = blockIdx.x, tid = threadIdx.x;
    const float4 f = ((const float4*)(xin + (size_t)row * DIM))[tid];
    float v[4] = {f.x, f.y, f.z, f.w};
    float s  = v[0] + v[1] + v[2] + v[3];
    float ss = v[0]*v[0] + v[1]*v[1] + v[2]*v[2] + v[3]*v[3];
    #pragma unroll
    for (int off = 32; off; off >>= 1) {
        s  += __shfl_down(s, off);
        ss += __shfl_down(ss, off);
    }
    __shared__ float red[2][4];
    const int wave = tid >> 6, lane = tid & 63;
    if (lane == 0) { red[0][wave] = s; red[1][wave] = ss; }
    __syncthreads();
    s  = red[0][0] + red[0][1] + red[0][2] + red[0][3];
    ss = red[1][0] + red[1][1] + red[1][2] + red[1][3];
    const float mean = s * (1.0f / DIM);
    const float var  = ss * (1.0f / DIM) - mean * mean;
    const float rstd = rsqrtf(var + 1e-5f);
    ushort_t o[4];
    #pragma unroll
    for (int i = 0; i < 4; i++) {
        const int col = tid * 4 + i;
        o[i] = f2b((v[i] - mean) * rstd * g[col] + be[col]);
    }
    uint2 u2;
    u2.x = (unsigned int)o[0] | ((unsigned int)o[1] << 16);
    u2.y = (unsigned int)o[2] | ((unsigned int)o[3] << 16);
    *(uint2*)(out + (size_t)row * DIM + tid * 4) = u2;
}

// ---------------------------------------------------------------- GEMM (Bt)
// BK=64 staged as two BK=32 slabs (keeps ldg16 contiguity [m104] and the benign
// 64B-row-stride LDS bank pattern [m98]); halves barrier-drain count vs BK=32.
#define ACT_NONE 0
#define ACT_ELU1 1
#define ACT_GELU 2
#define ACT_QKV  3   // cols < 2048 -> elu+1 (Q,K); cols >= 2048 -> none (V). block-uniform.

template<int ACT, bool BIAS, bool RES, bool OUTF32>
__global__ void __launch_bounds__(256, 4)
gemm_bt(const ushort_t* __restrict__ A, const ushort_t* __restrict__ Bt,
        const float* __restrict__ bias, const float* __restrict__ resid,
        void* __restrict__ Cout, int M, int N, int K)
{
    __shared__ __align__(16) ushort_t As[2][128 * 32];   // slab h: k-range [kt+32h, kt+32h+32)
    __shared__ __align__(16) ushort_t Bs[2][128 * 32];
    const int tid  = threadIdx.x;
    const int wave = tid >> 6, lane = tid & 63;
    const int bm = blockIdx.x * 128, bn = blockIdx.y * 128;
    const int wm = (wave >> 1) * 64, wn = (wave & 1) * 64;
    const int srow = tid >> 2;            // 0..63 staging row
    const int skp  = (tid & 3) * 8;       // 0,8,16,24 (elem offset in k)
    const int mrow = lane & 15, kq = (lane >> 4) * 8;
    const bool qkv_elu = (bn < 2048);     // wave-uniform (128 | 2048)

    f32x4 acc[4][4] = {};

    const size_t arow0 = (size_t)(bm + srow)      * K;
    const size_t arow1 = (size_t)(bm + srow + 64) * K;
    const size_t brow0 = (size_t)(bn + srow)      * K;
    const size_t brow1 = (size_t)(bn + srow + 64) * K;

    for (int kt = 0; kt < K; kt += 64) {
        __syncthreads();
        // each slab: 128 rows x 32 elems, LDS dest = 16B*tid (wave-uniform + lane*16)
        #pragma unroll
        for (int hh = 0; hh < 2; hh++) {
            const int ko = kt + hh * 32;
            ldg16(A  + arow0 + ko + skp, As[hh] + tid * 8);
            ldg16(A  + arow1 + ko + skp, As[hh] + 2048 + tid * 8);
            ldg16(Bt + brow0 + ko + skp, Bs[hh] + tid * 8);
            ldg16(Bt + brow1 + ko + skp, Bs[hh] + 2048 + tid * 8);
        }
        __syncthreads();
        #pragma unroll
        for (int hh = 0; hh < 2; hh++) {
            bf16x8 af[4], bfr[4];
            #pragma unroll
            for (int r = 0; r < 4; r++)
                af[r] = *(const bf16x8*)(As[hh] + (wm + r * 16 + mrow) * 32 + kq);
            #pragma unroll
            for (int c = 0; c < 4; c++)
                bfr[c] = *(const bf16x8*)(Bs[hh] + (wn + c * 16 + mrow) * 32 + kq);
            #pragma unroll
            for (int r = 0; r < 4; r++)
                #pragma unroll
                for (int c = 0; c < 4; c++)
                    acc[r][c] = __builtin_amdgcn_mfma_f32_16x16x32_bf16(af[r], bfr[c], acc[r][c], 0, 0, 0);
        }
    }

    // epilogue: C/D layout col=lane&15, row=(lane>>4)*4+reg   [m89/m91 verified]
    const int cr = (lane >> 4) * 4;
    const int cc = lane & 15;
    #pragma unroll
    for (int r = 0; r < 4; r++) {
        #pragma unroll
        for (int c = 0; c < 4; c++) {
            const int gc = bn + wn + c * 16 + cc;
            const float bv = BIAS ? bias[gc] : 0.0f;
            #pragma unroll
            for (int j = 0; j < 4; j++) {
                const int gr = bm + wm + r * 16 + cr + j;
                float vv = acc[r][c][j] + bv;
                if (ACT == ACT_ELU1) vv = fast_elu1(vv);
                if (ACT == ACT_GELU) vv = fast_gelu(vv);
                if (ACT == ACT_QKV)  vv = qkv_elu ? fast_elu1(vv) : vv;
                const size_t oidx = (size_t)gr * N + gc;
                if (RES) vv += resid[oidx];
                if (OUTF32) ((float*)Cout)[oidx] = vv;
                else        ((ushort_t*)Cout)[oidx] = f2b(vv);
            }
        }
    }
}

// ---------------------------------------------------------------- attention
// qkv buffer row stride = QSTR; K at col 1024, V at col 2048
__global__ void __launch_bounds__(256)
attn_phase1(const ushort_t* __restrict__ qkv,
            float* __restrict__ P, float* __restrict__ Ksum)
{
    const int c = blockIdx.x, h = blockIdx.y, b = blockIdx.z;
    __shared__ ushort_t Ks[64][68], Vs[64][68];
    const int tid = threadIdx.x;
    const size_t rowbase = (size_t)b * SEQ + c * 64;
    #pragma unroll
    for (int i = 0; i < 4; i++) {
        const int lin = tid + 256 * i;          // (t, d4) over 64x16
        const int t = lin >> 4, d4 = (lin & 15) * 4;
        const size_t gidx = (rowbase + t) * QSTR + h * HD + d4;
        *(uint2*)&Ks[t][d4] = *(const uint2*)(qkv + 1024 + gidx);
        *(uint2*)&Vs[t][d4] = *(const uint2*)(qkv + 2048 + gidx);
    }
    __syncthreads();
    const int d0 = (tid >> 4) * 4, e0 = (tid & 15) * 4;
    float acc[4][4] = {};
    for (int t = 0; t < 64; t++) {
        float kf[4], vf[4];
        unpack4(*(const uint2*)&Ks[t][d0], kf);
        unpack4(*(const uint2*)&Vs[t][e0], vf);
        #pragma unroll
        for (int i = 0; i < 4; i++)
            #pragma unroll
            for (int j = 0; j < 4; j++)
                acc[i][j] += kf[i] * vf[j];
    }
    const size_t pbase = (((size_t)b * NH + h) * NCHUNK + c) * 4096;
    #pragma unroll
    for (int i = 0; i < 4; i++) {
        float4 o; o.x = acc[i][0]; o.y = acc[i][1]; o.z = acc[i][2]; o.w = acc[i][3];
        *(float4*)(P + pbase + (size_t)(d0 + i) * 64 + e0) = o;
    }
    if (tid < 64) {
        float a = 0.0f;
        for (int t = 0; t < 64; t++) a += b2f(Ks[t][tid]);
        Ksum[(((size_t)b * NH + h) * NCHUNK + c) * 64 + tid] = a;
    }
}

// phase 1b: exclusive prefix over chunks, column-parallel.
__global__ void __launch_bounds__(256)
attn_prefix(float* __restrict__ P, float* __restrict__ Ksum)
{
    const int bh = blockIdx.y;
    const int e  = blockIdx.x * 256 + threadIdx.x;
    const size_t base = (size_t)bh * NCHUNK * 4096 + e;
    float acc = 0.0f;
    #pragma unroll
    for (int c = 0; c < NCHUNK; c++) {
        const float t = P[base + (size_t)c * 4096];
        P[base + (size_t)c * 4096] = acc;
        acc += t;
    }
    if (blockIdx.x == 0 && threadIdx.x < 64) {
        const size_t kb = (size_t)bh * NCHUNK * 64 + threadIdx.x;
        float a = 0.0f;
        #pragma unroll
        for (int c = 0; c < NCHUNK; c++) {
            const float t = Ksum[kb + c * 64];
            Ksum[kb + c * 64] = a;
            a += t;
        }
    }
}

// phase 2: out = (Q@M_prev + causal(QK^T)@V) / (Q@ksum_prev + rowsum(S) + 1e-6)
__global__ void __launch_bounds__(256)
attn_phase2(const ushort_t* __restrict__ qkv, const float* __restrict__ P,
            const float* __restrict__ Ksum, ushort_t* __restrict__ Out)
{
    const int c = blockIdx.x, h = blockIdx.y, b = blockIdx.z;
    const int tid = threadIdx.x;
    __shared__ ushort_t Qs[64][68], KsB[64][68], VsB[64][68];
    __shared__ float S[64][68];
    __shared__ float Mp[64][64];
    __shared__ float kp[64];
    __shared__ float partial[4][64];
    const size_t rowbase = (size_t)b * SEQ + c * 64;
    const size_t pbase = (((size_t)b * NH + h) * NCHUNK + c) * 4096;
    #pragma unroll
    for (int i = 0; i < 4; i++) {
        const int lin = tid + 256 * i;          // (t, d4) over 64x16
        const int t = lin >> 4, d4 = (lin & 15) * 4;
        const size_t gidx = (rowbase + t) * QSTR + h * HD + d4;
        *(uint2*)&Qs[t][d4]  = *(const uint2*)(qkv + gidx);
        *(uint2*)&KsB[t][d4] = *(const uint2*)(qkv + 1024 + gidx);
        *(uint2*)&VsB[t][d4] = *(const uint2*)(qkv + 2048 + gidx);
        *(float4*)&Mp[t][d4] = *(const float4*)(P + pbase + lin * 4);
    }
    if (tid < 64) kp[tid] = Ksum[(((size_t)b * NH + h) * NCHUNK + c) * 64 + tid];
    __syncthreads();

    const int t0 = (tid >> 4) * 4;
    const int c0 = (tid & 15) * 4;              // ii-block for S phase, e-block later

    // S = causal(Q K^T); masked entries written as 0
    {
        float accS[4][4] = {};
        for (int d4 = 0; d4 < 64; d4 += 4) {
            float qf[4][4], kf[4][4];
            #pragma unroll
            for (int i = 0; i < 4; i++) {
                unpack4(*(const uint2*)&Qs[t0 + i][d4], qf[i]);
                unpack4(*(const uint2*)&KsB[c0 + i][d4], kf[i]);
            }
            #pragma unroll
            for (int i = 0; i < 4; i++)
                #pragma unroll
                for (int j = 0; j < 4; j++)
                    #pragma unroll
                    for (int dd = 0; dd < 4; dd++)
                        accS[i][j] += qf[i][dd] * kf[j][dd];
        }
        #pragma unroll
        for (int i = 0; i < 4; i++) {
            float4 sv;
            sv.x = (c0 + 0 <= t0 + i) ? accS[i][0] : 0.0f;
            sv.y = (c0 + 1 <= t0 + i) ? accS[i][1] : 0.0f;
            sv.z = (c0 + 2 <= t0 + i) ? accS[i][2] : 0.0f;
            sv.w = (c0 + 3 <= t0 + i) ? accS[i][3] : 0.0f;
            *(float4*)&S[t0 + i][c0] = sv;
        }
    }
    __syncthreads();

    // den partials: quarter-range per thread
    {
        const int t = tid & 63, q = tid >> 6;
        const int base = q * 16;
        float a = 0.0f;
        #pragma unroll
        for (int ii = 0; ii < 16; ii++) a += S[t][base + ii];
        #pragma unroll
        for (int d = 0; d < 16; d++) a += b2f(Qs[t][base + d]) * kp[base + d];
        partial[q][t] = a;
    }
    __syncthreads();

    // out = S@V + Q@Mp, then /den
    float acc[4][4] = {};
    for (int ii = 0; ii < 64; ii++) {
        float vf[4];
        unpack4(*(const uint2*)&VsB[ii][c0], vf);
        #pragma unroll
        for (int i = 0; i < 4; i++) {
            const float s = S[t0 + i][ii];
            #pragma unroll
            for (int j = 0; j < 4; j++) acc[i][j] += s * vf[j];
        }
    }
    for (int d = 0; d < 64; d++) {
        const float4 mp = *(const float4*)&Mp[d][c0];
        #pragma unroll
        for (int i = 0; i < 4; i++) {
            const float qv = b2f(Qs[t0 + i][d]);
            acc[i][0] += qv * mp.x; acc[i][1] += qv * mp.y;
            acc[i][2] += qv * mp.z; acc[i][3] += qv * mp.w;
        }
    }
    #pragma unroll
    for (int i = 0; i < 4; i++) {
        const float dent = partial[0][t0 + i] + partial[1][t0 + i] +
                           partial[2][t0 + i] + partial[3][t0 + i] + 1e-6f;
        const float r = 1.0f / dent;
        ushort_t o[4];
        #pragma unroll
        for (int j = 0; j < 4; j++) o[j] = f2b(acc[i][j] * r);
        uint2 u2;
        u2.x = (unsigned int)o[0] | ((unsigned int)o[1] << 16);
        u2.y = (unsigned int)o[2] | ((unsigned int)o[3] << 16);
        *(uint2*)(Out + (rowbase + t0 + i) * DIM + h * HD + c0) = u2;
    }
}

// ---------------------------------------------------------------- launcher
extern "C" void kernel_launch(void* const* d_in, const int* in_sizes, int n_in,
                              void* d_out, int out_size, void* d_ws, size_t ws_size,
                              hipStream_t stream)
{
    const float* x      = (const float*)d_in[0];
    const float* Wq     = (const float*)d_in[1];
    const float* Wk     = (const float*)d_in[2];
    const float* Wv     = (const float*)d_in[3];
    const float* Wo     = (const float*)d_in[4];
    const float* ln1g   = (const float*)d_in[5];
    const float* ln1b   = (const float*)d_in[6];
    const float* ln2g   = (const float*)d_in[7];
    const float* ln2b   = (const float*)d_in[8];
    const float* cw1    = (const float*)d_in[9];
    const float* cb1    = (const float*)d_in[10];
    const float* cw2    = (const float*)d_in[11];
    const float* cb2    = (const float*)d_in[12];

    char* ws = (char*)d_ws;
    ushort_t* h     = (ushort_t*)(ws + OFF_H);
    ushort_t* qkv   = (ushort_t*)(ws + OFF_Q);
    float*    Pb    = (float*)(ws + OFF_P);
    float*    ksb   = (float*)(ws + OFF_KS);
    float*    x1    = (float*)(ws + OFF_X1);
    ushort_t* wqkvt = (ushort_t*)(ws + OFF_WQT);
    ushort_t* wot   = (ushort_t*)(ws + OFF_WOT);
    ushort_t* w1t   = (ushort_t*)(ws + OFF_W1T);
    ushort_t* w2t   = (ushort_t*)(ws + OFF_W2T);
    ushort_t* hid   = (ushort_t*)(ws + OFF_HIDB);
    float*    outp  = (float*)d_out;

    const dim3 tb(32, 8);
    // fused qkv weight^T: [3072][1024]
    transpose_f32_bf16<<<dim3(32, 32), tb, 0, stream>>>(Wq, wqkvt,                   DIM, DIM);
    transpose_f32_bf16<<<dim3(32, 32), tb, 0, stream>>>(Wk, wqkvt + 1024 * 1024,     DIM, DIM);
    transpose_f32_bf16<<<dim3(32, 32), tb, 0, stream>>>(Wv, wqkvt + 2 * 1024 * 1024, DIM, DIM);
    transpose_f32_bf16<<<dim3(32, 32), tb, 0, stream>>>(Wo, wot, DIM, DIM);
    for (int l = 0; l < 3; l++) {
        transpose_f32_bf16<<<dim3(128, 32), tb, 0, stream>>>(cw1 + (size_t)l * DIM * HID,
                                                             w1t + (size_t)l * HID * DIM, DIM, HID);
        transpose_f32_bf16<<<dim3(32, 128), tb, 0, stream>>>(cw2 + (size_t)l * HID * DIM,
                                                             w2t + (size_t)l * DIM * HID, HID, DIM);
    }

    ln_fwd<<<MROWS, 256, 0, stream>>>(x, ln1g, ln1b, h);

    // fused Q|K|V projection: [8192][3072], elu+1 on first 2048 cols
    gemm_bt<ACT_QKV, false, false, false><<<dim3(64, 24), 256, 0, stream>>>(
        h, wqkvt, nullptr, nullptr, qkv, MROWS, QSTR, DIM);

    attn_phase1<<<dim3(NCHUNK, NH, NB), 256, 0, stream>>>(qkv, Pb, ksb);
    attn_prefix<<<dim3(16, 64), 256, 0, stream>>>(Pb, ksb);
    attn_phase2<<<dim3(NCHUNK, NH, NB), 256, 0, stream>>>(qkv, Pb, ksb, h);  // h := attn out

    gemm_bt<ACT_NONE, false, true, true><<<dim3(64, 8), 256, 0, stream>>>(h, wot, nullptr, x, x1, MROWS, DIM, DIM);

    ln_fwd<<<MROWS, 256, 0, stream>>>(x1, ln2g, ln2b, h);

    const ushort_t* cur = h;
    for (int l = 0; l < 3; l++) {
        gemm_bt<ACT_GELU, true, false, false><<<dim3(64, 32), 256, 0, stream>>>(
            cur, w1t + (size_t)l * HID * DIM, cb1 + (size_t)l * HID, nullptr, hid, MROWS, HID, DIM);
        if (l < 2) {
            gemm_bt<ACT_NONE, true, false, false><<<dim3(64, 8), 256, 0, stream>>>(
                hid, w2t + (size_t)l * DIM * HID, cb2 + (size_t)l * DIM, nullptr, h, MROWS, DIM, HID);
            cur = h;
        } else {
            gemm_bt<ACT_NONE, true, true, true><<<dim3(64, 8), 256, 0, stream>>>(
                hid, w2t + (size_t)l * DIM * HID, cb2 + (size_t)l * DIM, x1, outp, MROWS, DIM, HID);
        }
    }
    (void)in_sizes; (void)n_in; (void)out_size; (void)ws_size;
}